// Round 2
// baseline (485.971 us; speedup 1.0000x reference)
//
#include <hip/hip_runtime.h>

// BNN conv3d forward: x (8,32,16,160,160) f32, w (32,32,1,3,3) f32
// out[n,o,d,h,w] = sum_i sum_{kh,kw} x[n,i,d,h+kh-1,w+kw-1] * we[o,i,kh,kw]
// we[o,i,kh,kw] = (mean_t |w[o,i,t]|) * sign(w[o,i,kh,kw])
//
// Implicit GEMM on mfma_f32_16x16x32_f16: M=16 spatial (consecutive w),
// N=16 out-ch (2 tiles for O=32), K=32 = all input channels, 9 K-steps (taps).
// Tile: 4 output rows x 80 w. LDS = 6 rows x 82 w x 32 ch f16 = 31488 B
// -> 5 blocks/CU (20 waves, 62% occupancy) vs round-1's 2 blocks/CU (23%).

typedef _Float16 half8 __attribute__((ext_vector_type(8)));
typedef float    floatx4 __attribute__((ext_vector_type(4)));

#define DHW  409600   // 16*160*160, per-channel stride in x/out
#define HW   25600    // 160*160

__global__ __launch_bounds__(256, 5) void bnn_conv3d_kernel(
        const float* __restrict__ x, const float* __restrict__ w,
        float* __restrict__ out) {
    // LDS: phase1 aliases first 9216 halfs for weight-frag staging; then the
    // whole array is the x tile: [r:6][w1:82][ch:32] f16 = 31488 B.
    __shared__ __align__(16) _Float16 ldsh[15744];

    const int tid  = threadIdx.x;
    const int lane = tid & 63;
    const int wid  = tid >> 6;

    const int bid = blockIdx.x;
    const int wt2 = bid & 1;           // w-half: 0 -> w[0,80), 1 -> w[80,160)
    const int ht  = (bid >> 1) % 40;   // h-tile
    const int nd  = bid / 80;
    const int d   = nd & 15;
    const int n   = nd >> 4;
    const int h0  = ht * 4;
    const int w0  = wt2 * 80;

    // ---------- phase 1: effective weights -> B fragments ------------------
    // B-frag for (tap t, o-tile p): lane l, elem j holds we[o=p*16+(l&15)][i=(l>>4)*8+j][t]
    #pragma unroll
    for (int p4 = 0; p4 < 4; ++p4) {
        const int oi = tid * 4 + p4;       // oi = o*32 + i, 0..1023
        const int o  = oi >> 5;
        const int i  = oi & 31;
        const float* wp = w + oi * 9;      // o*288 + i*9
        float s = 0.f;
        #pragma unroll
        for (int t = 0; t < 9; ++t) s += fabsf(wp[t]);
        s *= (1.f / 9.f);
        const int l = ((i >> 3) << 4) | (o & 15);
        const int p = o >> 4;
        const int j = i & 7;
        #pragma unroll
        for (int t = 0; t < 9; ++t) {
            const float v  = wp[t];
            const float sg = (v > 0.f) ? 1.f : ((v < 0.f) ? -1.f : 0.f);
            ldsh[((t * 2 + p) * 64 + l) * 8 + j] = (_Float16)(s * sg);
        }
    }
    __syncthreads();

    half8 wf[2][9];
    {
        const half8* fb = reinterpret_cast<const half8*>(ldsh);
        #pragma unroll
        for (int t = 0; t < 9; ++t) {
            wf[0][t] = fb[(t * 2 + 0) * 64 + lane];
            wf[1][t] = fb[(t * 2 + 1) * 64 + lane];
        }
    }
    __syncthreads();

    // ---------- phase 2: stage x tile as f16, swizzled ----------------------
    // logical (r, w1, ch): byte = (r*82+w1)*64 + ((ch>>3) ^ ((w1>>1)&3))*16 + (ch&7)*2
    // r: input row h0-1+r (0..5); w1: input col w0-1+w1 (0..81, halo included,
    // loaded from global with bounds check -> zeros at image edges).
    #pragma unroll 2
    for (int it = 0; it < 8; ++it) {
        const int idx = it * 256 + tid;    // 0..2047, 1968 = 6r * 4kg * 82w live
        if (idx < 1968) {
            const int wpos1 = idx % 82;
            const int rest  = idx / 82;    // 0..23
            const int kg    = rest & 3;
            const int r     = rest >> 2;
            const int h_in  = h0 - 1 + r;
            const int w_in  = w0 - 1 + wpos1;
            float v[8];
            if ((unsigned)h_in < 160u && (unsigned)w_in < 160u) {
                const float* src = x + ((n * 32 + kg * 8) * 16 + d) * HW
                                     + h_in * 160 + w_in;
                #pragma unroll
                for (int c = 0; c < 8; ++c) v[c] = src[c * DHW];
            } else {
                #pragma unroll
                for (int c = 0; c < 8; ++c) v[c] = 0.f;
            }
            half8 pk;
            #pragma unroll
            for (int c = 0; c < 8; ++c) pk[c] = (_Float16)v[c];
            const int skg = kg ^ ((wpos1 >> 1) & 3);
            *reinterpret_cast<half8*>(&ldsh[(r * 82 + wpos1) * 32 + skg * 8]) = pk;
        }
    }
    __syncthreads();

    // ---------- phase 3: MFMA ----------------------------------------------
    // A-frag: lane l elem j = x_lds(r=wid+kh, w1=wbase+(l&15)+kw, ch=(l>>4)*8+j)
    // D: row s=(l>>4)*4+reg (w offset), col o=l&15 (+16*p)
    const int s16 = lane & 15;
    const int kg  = lane >> 4;
    const int h   = h0 + wid;
    const int obase = (n * 32 + s16) * DHW + d * HW + h * 160 + w0 + kg * 4;

    #pragma unroll
    for (int wt = 0; wt < 5; ++wt) {
        const int wbase = wt * 16;
        floatx4 acc0 = {0.f, 0.f, 0.f, 0.f};
        floatx4 acc1 = {0.f, 0.f, 0.f, 0.f};
        #pragma unroll
        for (int kh = 0; kh < 3; ++kh) {
            const int rrow = (wid + kh) * 82;
            #pragma unroll
            for (int kw = 0; kw < 3; ++kw) {
                const int w1   = wbase + s16 + kw;
                const int aidx = (rrow + w1) * 32 + ((kg ^ ((w1 >> 1) & 3)) * 8);
                const half8 a  = *reinterpret_cast<const half8*>(&ldsh[aidx]);
                const int t = kh * 3 + kw;
                acc0 = __builtin_amdgcn_mfma_f32_16x16x32_f16(a, wf[0][t], acc0, 0, 0, 0);
                acc1 = __builtin_amdgcn_mfma_f32_16x16x32_f16(a, wf[1][t], acc1, 0, 0, 0);
            }
        }
        float* op = out + obase + wbase;
        *reinterpret_cast<floatx4*>(op)            = acc0;  // o = 0..15
        *reinterpret_cast<floatx4*>(op + 16 * DHW) = acc1;  // o = 16..31
    }
}

extern "C" void kernel_launch(void* const* d_in, const int* in_sizes, int n_in,
                              void* d_out, int out_size, void* d_ws, size_t ws_size,
                              hipStream_t stream) {
    const float* x = (const float*)d_in[0];
    const float* w = (const float*)d_in[1];
    float* out = (float*)d_out;
    // grid: 8 n * 16 d * 40 h-tiles * 2 w-halves
    bnn_conv3d_kernel<<<dim3(10240), dim3(256), 0, stream>>>(x, w, out);
}

// Round 3
// 223.931 us; speedup vs baseline: 2.1702x; 2.1702x over previous
//
#include <hip/hip_runtime.h>

// BNN conv3d forward: x (8,32,16,160,160) f32, w (32,32,1,3,3) f32
// out[n,o,d,h,w] = sum_i sum_{kh,kw} x[n,i,d,h+kh-1,w+kw-1] * we[o,i,kh,kw]
// we[o,i,kh,kw] = (mean_t |w[o,i,t]|) * sign(w[o,i,kh,kw])
//
// Implicit GEMM on mfma_f32_16x16x32_f16: M=16 spatial (consecutive w),
// N=16 out-ch (2 tiles for O=32), K=32 = all input channels, 9 K-steps (taps).
//
// Tile: 4 output rows x FULL 160 w (full-row is load-bearing: round-2's
// w-split doubled both FETCH (lost L3 halo absorption) and WRITE (split
// 128-B lines across blocks)). Block = 512 threads / 8 waves; wave =
// (row, w-half) -> 16 waves/CU at 2 blocks/CU instead of round-1's 8.

typedef _Float16 half8 __attribute__((ext_vector_type(8)));
typedef float    floatx4 __attribute__((ext_vector_type(4)));

#define DHW  409600   // 16*160*160, per-channel stride in x/out
#define HW   25600    // 160*160

__global__ __launch_bounds__(512, 4) void bnn_conv3d_kernel(
        const float* __restrict__ x, const float* __restrict__ w,
        float* __restrict__ out) {
    // LDS: phase1 aliases first 9216 halfs for weight-frag staging; then the
    // whole array is the x tile: [r:6][w1:162][ch:32] f16 = 62208 B.
    __shared__ __align__(16) _Float16 ldsh[31104];

    const int tid  = threadIdx.x;
    const int lane = tid & 63;
    const int wid  = tid >> 6;

    const int bid = blockIdx.x;
    const int ht  = bid % 40;          // h-tile
    const int nd  = bid / 40;
    const int d   = nd & 15;
    const int n   = nd >> 4;
    const int h0  = ht * 4;

    // ---------- phase 1: effective weights -> B fragments ------------------
    // B-frag for (tap t, o-tile p): lane l, elem j holds we[o=p*16+(l&15)][i=(l>>4)*8+j][t]
    #pragma unroll
    for (int p4 = 0; p4 < 2; ++p4) {
        const int oi = tid * 2 + p4;       // oi = o*32 + i, 0..1023
        const int o  = oi >> 5;
        const int i  = oi & 31;
        const float* wp = w + oi * 9;      // o*288 + i*9
        float s = 0.f;
        #pragma unroll
        for (int t = 0; t < 9; ++t) s += fabsf(wp[t]);
        s *= (1.f / 9.f);
        const int l = ((i >> 3) << 4) | (o & 15);
        const int p = o >> 4;
        const int j = i & 7;
        #pragma unroll
        for (int t = 0; t < 9; ++t) {
            const float v  = wp[t];
            const float sg = (v > 0.f) ? 1.f : ((v < 0.f) ? -1.f : 0.f);
            ldsh[((t * 2 + p) * 64 + l) * 8 + j] = (_Float16)(s * sg);
        }
    }
    __syncthreads();

    half8 wf[2][9];
    {
        const half8* fb = reinterpret_cast<const half8*>(ldsh);
        #pragma unroll
        for (int t = 0; t < 9; ++t) {
            wf[0][t] = fb[(t * 2 + 0) * 64 + lane];
            wf[1][t] = fb[(t * 2 + 1) * 64 + lane];
        }
    }
    __syncthreads();

    // ---------- phase 2: stage x tile as f16, swizzled ----------------------
    // logical (r, w1, ch): byte = (r*162+w1)*64 + ((ch>>3) ^ ((w1>>1)&3))*16 + (ch&7)*2
    // r = input row h0-1+r ; w1 = w+1 (w1=0 and 161 are zero halo)

    // zero halo columns w1 in {0,161}: 12 cells x 64 B
    if (tid < 192) {
        const int pos = tid >> 4, word = tid & 15;
        const int r   = pos >> 1;
        const int w1  = (pos & 1) ? 161 : 0;
        reinterpret_cast<unsigned int*>(ldsh)[(r * 162 + w1) * 16 + word] = 0u;
    }
    // main staging: thread owns (r, kg=ch-group of 8, wpos); 8 coalesced scalar
    // loads (lane = wpos), pack to half8, one ds_write_b128.
    #pragma unroll 2
    for (int it = 0; it < 8; ++it) {
        const int idx = it * 512 + tid;    // 0..4095, 3840 = 6r * 4kg * 160w live
        if (idx < 3840) {
            const int wpos = idx % 160;
            const int rest = idx / 160;    // 0..23
            const int kg   = rest & 3;
            const int r    = rest >> 2;
            const int h_in = h0 - 1 + r;
            float v[8];
            if ((unsigned)h_in < 160u) {
                const float* src = x + ((n * 32 + kg * 8) * 16 + d) * HW
                                     + h_in * 160 + wpos;
                #pragma unroll
                for (int c = 0; c < 8; ++c) v[c] = src[c * DHW];
            } else {
                #pragma unroll
                for (int c = 0; c < 8; ++c) v[c] = 0.f;
            }
            half8 pk;
            #pragma unroll
            for (int c = 0; c < 8; ++c) pk[c] = (_Float16)v[c];
            const int w1  = wpos + 1;
            const int skg = kg ^ ((w1 >> 1) & 3);
            *reinterpret_cast<half8*>(&ldsh[(r * 162 + w1) * 32 + skg * 8]) = pk;
        }
    }
    __syncthreads();

    // ---------- phase 3: MFMA ----------------------------------------------
    // wave wid: row = wid&3, w-half = wid>>2 (5 MFMA tiles each).
    // A-frag: lane l elem j = x_lds(r=row+kh, w1=wbase+(l&15)+kw, ch=(l>>4)*8+j)
    // D: row s=(l>>4)*4+reg (w offset), col o=l&15 (+16*p)
    const int s16   = lane & 15;
    const int kg    = lane >> 4;
    const int row   = wid & 3;
    const int whalf = wid >> 2;
    const int h     = h0 + row;
    const int obase = (n * 32 + s16) * DHW + d * HW + h * 160 + kg * 4;

    #pragma unroll
    for (int wtl = 0; wtl < 5; ++wtl) {
        const int wbase = (whalf * 5 + wtl) * 16;
        floatx4 acc0 = {0.f, 0.f, 0.f, 0.f};
        floatx4 acc1 = {0.f, 0.f, 0.f, 0.f};
        #pragma unroll
        for (int kh = 0; kh < 3; ++kh) {
            const int rrow = (row + kh) * 162;
            #pragma unroll
            for (int kw = 0; kw < 3; ++kw) {
                const int w1   = wbase + s16 + kw;
                const int aidx = (rrow + w1) * 32 + ((kg ^ ((w1 >> 1) & 3)) * 8);
                const half8 a  = *reinterpret_cast<const half8*>(&ldsh[aidx]);
                const int t = kh * 3 + kw;
                acc0 = __builtin_amdgcn_mfma_f32_16x16x32_f16(a, wf[0][t], acc0, 0, 0, 0);
                acc1 = __builtin_amdgcn_mfma_f32_16x16x32_f16(a, wf[1][t], acc1, 0, 0, 0);
            }
        }
        float* op = out + obase + wbase;
        *reinterpret_cast<floatx4*>(op)            = acc0;  // o = 0..15
        *reinterpret_cast<floatx4*>(op + 16 * DHW) = acc1;  // o = 16..31
    }
}

extern "C" void kernel_launch(void* const* d_in, const int* in_sizes, int n_in,
                              void* d_out, int out_size, void* d_ws, size_t ws_size,
                              hipStream_t stream) {
    const float* x = (const float*)d_in[0];
    const float* w = (const float*)d_in[1];
    float* out = (float*)d_out;
    // grid: 8 n * 16 d * 40 h-tiles (full 160-w rows per block)
    bnn_conv3d_kernel<<<dim3(5120), dim3(512), 0, stream>>>(x, w, out);
}